// Round 1
// baseline (430.790 us; speedup 1.0000x reference)
//
#include <hip/hip_runtime.h>
#include <hip/hip_bf16.h>
#include <stdint.h>

// KroneckerMarkerCovariance: out = (V (x) V (x) V_C) D^-1 (V (x) V (x) V_C)^T v
// n=128, C=32, m=64.
// Decomposition:
//   pass1: W[k][mm][j][i] = sum_c v[i][j][c][mm] * VC[c][k]          (bf16)
//   pass2: per (k,mm): S = V ((V^T B V) ./ E_k) V^T  via 4 bf16 MFMA GEMMs,
//          U[k][mm][i][j] = S[i][j]                                   (fp32)
//   pass3: out[i][j][c][mm] = sum_k U[k][mm][i][j] * VC[c][k]         (fp32)
// (marker un-rotation commutes with spatial un-rotations, so it is hoisted
//  out of the per-(k,mm) chain)

typedef unsigned short ushort_t;
typedef __attribute__((ext_vector_type(8))) short short8;   // 8 bf16 = 4 VGPRs
typedef __attribute__((ext_vector_type(4))) float f32x4;

__device__ __forceinline__ unsigned short f2bf(float f) {
  union { float f; uint32_t u; } v; v.f = f;
  uint32_t u = v.u;
  return (unsigned short)((u + 0x7fffu + ((u >> 16) & 1u)) >> 16);  // RNE
}

// ---------------- prep: rte[k][a][b] = 1/te[a][b][k]; V -> bf16 (plain + transposed)
__global__ __launch_bounds__(256) void prep_kernel(
    const float* __restrict__ te, const float* __restrict__ Vg,
    float* __restrict__ rte, ushort_t* __restrict__ Vhg, ushort_t* __restrict__ Vtg) {
  int b = blockIdx.x, t = threadIdx.x;
  if (b < 64) {
    int ab = b * 256 + t;                    // (a*128+b) flat, 0..16383
    #pragma unroll
    for (int k = 0; k < 32; ++k)
      rte[k * 16384 + ab] = 1.0f / te[ab * 32 + k];
  } else {
    int base = (b - 64) * 4096;
    #pragma unroll
    for (int e = 0; e < 16; ++e) {
      int idx = base + e * 256 + t;          // 0..16383
      float f = Vg[idx];
      unsigned short us = f2bf(f);
      Vhg[idx] = us;                               // Vh[r][c] = V[r][c]
      Vtg[(idx & 127) * 128 + (idx >> 7)] = us;    // Vt[c][r] = V[r][c]
    }
  }
}

// ---------------- pass1: marker rotation + transpose to W[k][mm][j][i] (bf16)
__global__ __launch_bounds__(256) void pass1_kernel(
    const float* __restrict__ v, const float* __restrict__ VC, ushort_t* __restrict__ W) {
  __shared__ float Xs[8][32][32];   // [ii][c][mm] 32KB
  __shared__ float VCs[32][32];     // [c][k]      4KB
  int t  = threadIdx.x;
  int id = blockIdx.x;
  int j  = id & 127;
  int it = (id >> 7) & 3;
  int mt = id >> 9;
  int i0 = it * 32, mm0 = mt * 32;

  #pragma unroll
  for (int e = 0; e < 4; ++e) {
    int idx = e * 256 + t;
    VCs[idx >> 5][idx & 31] = VC[idx];
  }
  __syncthreads();

  int mm = t & 31;
  int kq = t >> 5;                  // 0..7, thread owns k = kq*4 + 0..3

  for (int blk = 0; blk < 4; ++blk) {
    int ib = i0 + blk * 8;
    // stage 8 rows of i: Xs[ii][c][mm]
    #pragma unroll
    for (int e = 0; e < 8; ++e) {
      int idx4 = e * 256 + t;                 // 2048 float4 = 8192 floats
      int ii = idx4 >> 8;
      int c  = (idx4 >> 3) & 31;
      int mq = idx4 & 7;
      float4 src = *(const float4*)(v + ((((size_t)(ib + ii) * 128 + j) * 32 + c) * 64 + mm0 + mq * 4));
      *(float4*)&Xs[ii][c][mq * 4] = src;
    }
    __syncthreads();

    float acc[4][8];
    #pragma unroll
    for (int e = 0; e < 4; ++e)
      #pragma unroll
      for (int ii = 0; ii < 8; ++ii) acc[e][ii] = 0.f;

    for (int c = 0; c < 32; ++c) {
      float xv[8];
      #pragma unroll
      for (int ii = 0; ii < 8; ++ii) xv[ii] = Xs[ii][c][mm];
      #pragma unroll
      for (int e = 0; e < 4; ++e) {
        float w = VCs[c][kq * 4 + e];
        #pragma unroll
        for (int ii = 0; ii < 8; ++ii) acc[e][ii] += w * xv[ii];
      }
    }

    // write 8 consecutive i as one 16B store per k
    #pragma unroll
    for (int e = 0; e < 4; ++e) {
      int k = kq * 4 + e;
      uint32_t w0 = (uint32_t)f2bf(acc[e][0]) | ((uint32_t)f2bf(acc[e][1]) << 16);
      uint32_t w1 = (uint32_t)f2bf(acc[e][2]) | ((uint32_t)f2bf(acc[e][3]) << 16);
      uint32_t w2 = (uint32_t)f2bf(acc[e][4]) | ((uint32_t)f2bf(acc[e][5]) << 16);
      uint32_t w3 = (uint32_t)f2bf(acc[e][6]) | ((uint32_t)f2bf(acc[e][7]) << 16);
      *(uint4*)(W + (((size_t)(k * 64 + mm0 + mm) * 128 + j) * 128 + ib)) =
          make_uint4(w0, w1, w2, w3);
    }
    __syncthreads();
  }
}

// ---------------- pass2: per-(k,mm) 4-GEMM chain, bf16 MFMA
__device__ __forceinline__ void gemm128(const ushort_t (*__restrict__ Am)[136],
                                        const ushort_t (*__restrict__ Bm)[136],
                                        int r0, int c0, int lr, int lk, f32x4 acc[2][4]) {
  #pragma unroll
  for (int fr = 0; fr < 2; ++fr)
    #pragma unroll
    for (int fc = 0; fc < 4; ++fc) acc[fr][fc] = (f32x4){0.f, 0.f, 0.f, 0.f};
  #pragma unroll
  for (int kb = 0; kb < 4; ++kb) {
    short8 a[2], b[4];
    #pragma unroll
    for (int fr = 0; fr < 2; ++fr)
      a[fr] = *(const short8*)&Am[r0 + fr * 16 + lr][kb * 32 + lk];
    #pragma unroll
    for (int fc = 0; fc < 4; ++fc)
      b[fc] = *(const short8*)&Bm[c0 + fc * 16 + lr][kb * 32 + lk];
    #pragma unroll
    for (int fr = 0; fr < 2; ++fr)
      #pragma unroll
      for (int fc = 0; fc < 4; ++fc)
        acc[fr][fc] = __builtin_amdgcn_mfma_f32_16x16x32_bf16(a[fr], b[fc], acc[fr][fc], 0, 0, 0);
  }
}

__global__ __launch_bounds__(512, 4) void pass2_kernel(
    const ushort_t* __restrict__ W, const ushort_t* __restrict__ Vhg,
    const ushort_t* __restrict__ Vtg, const float* __restrict__ rte,
    float* __restrict__ U) {
  __shared__ ushort_t Ab[128][136];   // data buffer (W -> S1 -> S3t -> S4)
  __shared__ ushort_t Vb[128][136];   // Vt for G1/G2, then Vh for G3/G4
  int t = threadIdx.x;
  int blk = blockIdx.x;               // k*64 + mm
  int kk = blk >> 6;

  {
    const uint4* Wp = (const uint4*)W + (size_t)blk * 2048;
    const uint4* Vp = (const uint4*)Vtg;
    #pragma unroll
    for (int e = 0; e < 4; ++e) {
      int idx = e * 512 + t;          // 0..2047
      int row = idx >> 4, part = idx & 15;
      *(uint4*)&Ab[row][part * 8] = Wp[idx];
      *(uint4*)&Vb[row][part * 8] = Vp[idx];
    }
  }
  __syncthreads();

  int wave = t >> 6, lane = t & 63;
  int r0 = (wave >> 1) * 32, c0 = (wave & 1) * 64;   // 8 waves: 4x2 quadrants of 32x64
  int lr = lane & 15;
  int lk = (lane >> 4) * 8;            // k-element offset within 32-wide k-block
  int rowreg = (lane >> 4) * 4;        // C/D row base within 16x16 fragment

  f32x4 acc[2][4];

  // G1: S1[a][j] = sum_i V[i][a] * B[i][j]   (A = Vt, B-op = W stored [j][i])
  gemm128(Vb, Ab, r0, c0, lr, lk, acc);
  __syncthreads();
  #pragma unroll
  for (int fr = 0; fr < 2; ++fr)
    #pragma unroll
    for (int fc = 0; fc < 4; ++fc)
      #pragma unroll
      for (int r = 0; r < 4; ++r)
        Ab[r0 + fr * 16 + rowreg + r][c0 + fc * 16 + lr] = f2bf(acc[fr][fc][r]);
  __syncthreads();

  // G2: S2[a][b] = sum_j S1[a][j] V[j][b]   (A = S1, B-op = V stored as Vt[b][j])
  gemm128(Ab, Vb, r0, c0, lr, lk, acc);
  // divide by eigenvalues (multiply by reciprocal table, coalesced over b)
  #pragma unroll
  for (int fr = 0; fr < 2; ++fr)
    #pragma unroll
    for (int fc = 0; fc < 4; ++fc)
      #pragma unroll
      for (int r = 0; r < 4; ++r) {
        int a = r0 + fr * 16 + rowreg + r;
        int bcol = c0 + fc * 16 + lr;
        acc[fr][fc][r] *= rte[(size_t)kk * 16384 + a * 128 + bcol];
      }
  __syncthreads();
  // write S3 transposed: Ab[b][a] (packed 4 consecutive a = 8B), reload Vb = Vh
  #pragma unroll
  for (int fr = 0; fr < 2; ++fr)
    #pragma unroll
    for (int fc = 0; fc < 4; ++fc) {
      int bcol = c0 + fc * 16 + lr;
      int abase = r0 + fr * 16 + rowreg;
      uint32_t lo = (uint32_t)f2bf(acc[fr][fc][0]) | ((uint32_t)f2bf(acc[fr][fc][1]) << 16);
      uint32_t hi = (uint32_t)f2bf(acc[fr][fc][2]) | ((uint32_t)f2bf(acc[fr][fc][3]) << 16);
      *(uint2*)&Ab[bcol][abase] = make_uint2(lo, hi);
    }
  {
    const uint4* Vp = (const uint4*)Vhg;
    #pragma unroll
    for (int e = 0; e < 4; ++e) {
      int idx = e * 512 + t;
      int row = idx >> 4, part = idx & 15;
      *(uint4*)&Vb[row][part * 8] = Vp[idx];
    }
  }
  __syncthreads();

  // G3: S4[i][b] = sum_a V[i][a] S3[a][b]   (A = Vh, B-op = S3t[b][a])
  gemm128(Vb, Ab, r0, c0, lr, lk, acc);
  __syncthreads();
  #pragma unroll
  for (int fr = 0; fr < 2; ++fr)
    #pragma unroll
    for (int fc = 0; fc < 4; ++fc)
      #pragma unroll
      for (int r = 0; r < 4; ++r)
        Ab[r0 + fr * 16 + rowreg + r][c0 + fc * 16 + lr] = f2bf(acc[fr][fc][r]);
  __syncthreads();

  // G4: S5[i][j] = sum_b S4[i][b] V[j][b]   (A = S4, B-op = V^T stored as Vh[j][b])
  gemm128(Ab, Vb, r0, c0, lr, lk, acc);

  float* Ub = U + (size_t)blk * 16384;
  #pragma unroll
  for (int fr = 0; fr < 2; ++fr)
    #pragma unroll
    for (int fc = 0; fc < 4; ++fc)
      #pragma unroll
      for (int r = 0; r < 4; ++r)
        Ub[(r0 + fr * 16 + rowreg + r) * 128 + (c0 + fc * 16 + lr)] = acc[fr][fc][r];
}

// ---------------- pass3: marker un-rotation + transpose back to [i][j][c][mm]
__global__ __launch_bounds__(512, 2) void pass3_kernel(
    const float* __restrict__ U, const float* __restrict__ VC, float* __restrict__ out) {
  __shared__ float Ub[32][32][20];   // [k][jj][mmi] (pad 16->20) 80KB
  __shared__ float VCt[32][32];      // [k][c] 4KB
  int t  = threadIdx.x;
  int id = blockIdx.x;
  int i  = id & 127;
  int jt = (id >> 7) & 3, mt = id >> 9;
  int j0 = jt * 32, mm0 = mt * 16;

  #pragma unroll
  for (int e = 0; e < 2; ++e) {
    int idx = e * 512 + t;               // c*32+k
    VCt[idx & 31][idx >> 5] = VC[idx];
  }
  // stage U[k][mm0+mmi][i][j0..j0+31] -> Ub[k][jj][mmi] (transpose in LDS)
  #pragma unroll
  for (int e = 0; e < 8; ++e) {
    int idx4 = e * 512 + t;              // 0..4095
    int fr = idx4 >> 3;                  // k*16 + mmi
    int part = idx4 & 7;
    int k = fr >> 4, mmi = fr & 15;
    float4 u = *(const float4*)(U + ((((size_t)(k * 64 + mm0 + mmi) * 128) + i) * 128 + j0 + part * 4));
    Ub[k][part * 4 + 0][mmi] = u.x;
    Ub[k][part * 4 + 1][mmi] = u.y;
    Ub[k][part * 4 + 2][mmi] = u.z;
    Ub[k][part * 4 + 3][mmi] = u.w;
  }
  __syncthreads();

  int jj = t & 31, ch = t >> 5;          // ch 0..15, owns c = ch*2 + {0,1}
  float acc[16][2];
  #pragma unroll
  for (int q = 0; q < 16; ++q) { acc[q][0] = 0.f; acc[q][1] = 0.f; }

  for (int k = 0; k < 32; ++k) {
    float vc0 = VCt[k][ch * 2];
    float vc1 = VCt[k][ch * 2 + 1];
    #pragma unroll
    for (int m4 = 0; m4 < 4; ++m4) {
      float4 u = *(const float4*)&Ub[k][jj][m4 * 4];
      const float* up = (const float*)&u;
      #pragma unroll
      for (int e = 0; e < 4; ++e) {
        acc[m4 * 4 + e][0] += vc0 * up[e];
        acc[m4 * 4 + e][1] += vc1 * up[e];
      }
    }
  }

  #pragma unroll
  for (int e2 = 0; e2 < 2; ++e2) {
    int c = ch * 2 + e2;
    #pragma unroll
    for (int m4 = 0; m4 < 4; ++m4) {
      float4 o;
      o.x = acc[m4 * 4 + 0][e2];
      o.y = acc[m4 * 4 + 1][e2];
      o.z = acc[m4 * 4 + 2][e2];
      o.w = acc[m4 * 4 + 3][e2];
      *(float4*)(out + ((((size_t)i * 128 + j0 + jj) * 32 + c) * 64 + mm0 + m4 * 4)) = o;
    }
  }
}

extern "C" void kernel_launch(void* const* d_in, const int* in_sizes, int n_in,
                              void* d_out, int out_size, void* d_ws, size_t ws_size,
                              hipStream_t stream) {
  (void)in_sizes; (void)n_in; (void)out_size; (void)ws_size;
  const float* v  = (const float*)d_in[0];
  const float* VC = (const float*)d_in[1];
  const float* Vg = (const float*)d_in[2];
  const float* te = (const float*)d_in[3];
  float* out = (float*)d_out;

  char* ws = (char*)d_ws;
  ushort_t* W   = (ushort_t*)ws;                                     // 67,108,864 B
  float*    U   = (float*)(ws + 67108864);                           // 134,217,728 B
  float*    rte = (float*)(ws + 67108864 + 134217728);               // 2,097,152 B
  ushort_t* Vhg = (ushort_t*)(ws + 203423744);                       // 32,768 B
  ushort_t* Vtg = (ushort_t*)(ws + 203456512);                       // 32,768 B
  // total ws use: 203,489,280 B

  prep_kernel<<<68, 256, 0, stream>>>(te, Vg, rte, Vhg, Vtg);
  pass1_kernel<<<1024, 256, 0, stream>>>(v, VC, W);
  pass2_kernel<<<2048, 512, 0, stream>>>(W, Vhg, Vtg, rte, U);
  pass3_kernel<<<2048, 512, 0, stream>>>(U, VC, out);
}

// Round 2
// 400.363 us; speedup vs baseline: 1.0760x; 1.0760x over previous
//
#include <hip/hip_runtime.h>
#include <stdint.h>

// KroneckerMarkerCovariance, n=128, C=32, m=64.
//   prep: rte[k][a][b] = 1/te[a][b][k];  V -> bf16 (Vh row-major, Vt transposed)
//   k1:   W[k*64+mm][i*128+j] = bf16( sum_c v[i][j][c][mm] * VC[c][k] )
//         (marker rotate fused with (ji)<->(km) transpose; all HBM 64B-sector aligned)
//   k3:   per (k,mm): 4-GEMM chain  V ((V^T B V)./E) V^T  in bf16 MFMA.
//         Input tile is B[i][j]; since E is symmetric (lam_a*lam_b), the
//         unchanged chain yields S^T, i.e. U[km][j*128+i] = S[i][j].  U bf16.
//   k5:   out[i][j][c][mm] = sum_k U[km][j*128+i] * VC[c][k]   (fp32 out)

typedef unsigned short ushort_t;
typedef __attribute__((ext_vector_type(8))) short short8;   // 8 bf16
typedef __attribute__((ext_vector_type(4))) float f32x4;

__device__ __forceinline__ ushort_t f2bf(float f) {
  union { float f; uint32_t u; } v; v.f = f;
  uint32_t u = v.u;
  return (ushort_t)((u + 0x7fffu + ((u >> 16) & 1u)) >> 16);  // RNE
}
__device__ __forceinline__ uint32_t pk2(float a, float b) {
  return (uint32_t)f2bf(a) | ((uint32_t)f2bf(b) << 16);
}
__device__ __forceinline__ float bf2f(ushort_t u) {
  union { uint32_t x; float f; } v; v.x = (uint32_t)u << 16; return v.f;
}

// ---------------- prep ----------------
__global__ __launch_bounds__(256) void prep_kernel(
    const float* __restrict__ te, const float* __restrict__ Vg,
    float* __restrict__ rte, ushort_t* __restrict__ Vhg, ushort_t* __restrict__ Vtg) {
  int b = blockIdx.x, t = threadIdx.x;
  if (b < 256) {
    int id = b * 256 + t;            // 0..65535, each does 8 consecutive outputs
    int o0 = id * 8;                 // rte flat = k*16384 + ab
    int k = o0 >> 14, ab0 = o0 & 16383;
    float r[8];
    #pragma unroll
    for (int e = 0; e < 8; ++e) r[e] = 1.0f / te[(ab0 + e) * 32 + k];
    *(float4*)(rte + o0)     = make_float4(r[0], r[1], r[2], r[3]);
    *(float4*)(rte + o0 + 4) = make_float4(r[4], r[5], r[6], r[7]);
  } else {
    int base = (b - 256) * 4096 + t;
    #pragma unroll
    for (int e = 0; e < 16; ++e) {
      int idx = base + e * 256;      // 0..16383
      ushort_t us = f2bf(Vg[idx]);
      Vhg[idx] = us;                               // Vh[r][c] = V[r][c]
      Vtg[(idx & 127) * 128 + (idx >> 7)] = us;    // Vt[c][r] = V[r][c]
    }
  }
}

// ---------------- k1: marker rotate + transpose ----------------
// block: 32 consecutive ji (= i*128+j), 16-mm chunk; 256 threads.
__global__ __launch_bounds__(256) void k1_rot_t(
    const float* __restrict__ v, const float* __restrict__ VC, ushort_t* __restrict__ W) {
  __shared__ ushort_t Xs[32 * 520];   // [jj][c*16+mmi], jj-stride 520 (bank spread) 33280B
  __shared__ ushort_t Wt[512 * 32];   // [k*16+mmi][jj]  32768B
  __shared__ float VCs[1024];         // [c][k]
  int t = threadIdx.x, bid = blockIdx.x;
  int jc = bid >> 2, mt = bid & 3;
  int ji0 = jc * 32, mm0 = mt * 16;

  #pragma unroll
  for (int e = 0; e < 4; ++e) VCs[e * 256 + t] = VC[e * 256 + t];

  // stage v slab -> bf16 Xs
  #pragma unroll
  for (int e = 0; e < 4; ++e) {
    int q = e * 256 + t;             // 0..1023
    int jj = q >> 5, c = q & 31;
    const float* src = v + (size_t)(ji0 + jj) * 2048 + c * 64 + mm0;
    float4 f0 = *(const float4*)(src);
    float4 f1 = *(const float4*)(src + 4);
    float4 f2 = *(const float4*)(src + 8);
    float4 f3 = *(const float4*)(src + 12);
    uint4 lo = make_uint4(pk2(f0.x, f0.y), pk2(f0.z, f0.w), pk2(f1.x, f1.y), pk2(f1.z, f1.w));
    uint4 hi = make_uint4(pk2(f2.x, f2.y), pk2(f2.z, f2.w), pk2(f3.x, f3.y), pk2(f3.z, f3.w));
    ushort_t* dst = &Xs[jj * 520 + c * 16];
    *(uint4*)dst = lo;
    *(uint4*)(dst + 8) = hi;
  }
  __syncthreads();

  // compute: thread (jj = t&31, kq = t>>5) -> acc over 4 k x 16 mm
  int jj = t & 31, kq = t >> 5;
  float acc[4][16];
  #pragma unroll
  for (int e = 0; e < 4; ++e)
    #pragma unroll
    for (int q = 0; q < 16; ++q) acc[e][q] = 0.f;

  for (int c = 0; c < 32; ++c) {
    const ushort_t* xp = &Xs[jj * 520 + c * 16];
    short8 x0 = *(const short8*)xp;
    short8 x1 = *(const short8*)(xp + 8);
    float vc0 = VCs[c * 32 + kq * 4 + 0];
    float vc1 = VCs[c * 32 + kq * 4 + 1];
    float vc2 = VCs[c * 32 + kq * 4 + 2];
    float vc3 = VCs[c * 32 + kq * 4 + 3];
    #pragma unroll
    for (int q = 0; q < 8; ++q) {
      float xf = bf2f((ushort_t)x0[q]);
      acc[0][q] += vc0 * xf; acc[1][q] += vc1 * xf;
      acc[2][q] += vc2 * xf; acc[3][q] += vc3 * xf;
    }
    #pragma unroll
    for (int q = 0; q < 8; ++q) {
      float xf = bf2f((ushort_t)x1[q]);
      acc[0][8 + q] += vc0 * xf; acc[1][8 + q] += vc1 * xf;
      acc[2][8 + q] += vc2 * xf; acc[3][8 + q] += vc3 * xf;
    }
  }

  // scatter acc into Wt (u16 writes, lanes along jj: conflict-free)
  #pragma unroll
  for (int e = 0; e < 4; ++e)
    #pragma unroll
    for (int q = 0; q < 16; ++q)
      Wt[((kq * 4 + e) * 16 + q) * 32 + jj] = f2bf(acc[e][q]);
  __syncthreads();

  // write out: row = k*16+mmi (64B per row), 4 parts of 16B
  int part = t & 3, rq = t >> 2;
  #pragma unroll
  for (int e = 0; e < 8; ++e) {
    int row = e * 64 + rq;
    int k = row >> 4, mmi = row & 15;
    uint4 d = *(const uint4*)&Wt[row * 32 + part * 8];
    *(uint4*)(W + (size_t)(k * 64 + mm0 + mmi) * 16384 + ji0 + part * 8) = d;
  }
}

// ---------------- k3: per-(k,mm) 4-GEMM chain ----------------
__device__ __forceinline__ void gemm128(const ushort_t (*__restrict__ Am)[136],
                                        const ushort_t (*__restrict__ Bm)[136],
                                        int r0, int c0, int lr, int lk, f32x4 acc[2][4]) {
  #pragma unroll
  for (int fr = 0; fr < 2; ++fr)
    #pragma unroll
    for (int fc = 0; fc < 4; ++fc) acc[fr][fc] = (f32x4){0.f, 0.f, 0.f, 0.f};
  #pragma unroll
  for (int kb = 0; kb < 4; ++kb) {
    short8 a[2], b[4];
    #pragma unroll
    for (int fr = 0; fr < 2; ++fr)
      a[fr] = *(const short8*)&Am[r0 + fr * 16 + lr][kb * 32 + lk];
    #pragma unroll
    for (int fc = 0; fc < 4; ++fc)
      b[fc] = *(const short8*)&Bm[c0 + fc * 16 + lr][kb * 32 + lk];
    #pragma unroll
    for (int fr = 0; fr < 2; ++fr)
      #pragma unroll
      for (int fc = 0; fc < 4; ++fc)
        acc[fr][fc] = __builtin_amdgcn_mfma_f32_16x16x32_bf16(a[fr], b[fc], acc[fr][fc], 0, 0, 0);
  }
}

__global__ __launch_bounds__(512, 2) void k3_chain(
    const ushort_t* __restrict__ W, const ushort_t* __restrict__ Vhg,
    const ushort_t* __restrict__ Vtg, const float* __restrict__ rte,
    ushort_t* __restrict__ U) {
  __shared__ ushort_t Ab[128][136];
  __shared__ ushort_t Vb[128][136];
  int t = threadIdx.x;
  int blk = blockIdx.x;               // k*64 + mm
  int kk = blk >> 6;

  {
    const uint4* Wp = (const uint4*)W + (size_t)blk * 2048;
    const uint4* Vp = (const uint4*)Vtg;
    #pragma unroll
    for (int e = 0; e < 4; ++e) {
      int idx = e * 512 + t;
      int row = idx >> 4, part = idx & 15;
      *(uint4*)&Ab[row][part * 8] = Wp[idx];
      *(uint4*)&Vb[row][part * 8] = Vp[idx];
    }
  }
  __syncthreads();

  int wave = t >> 6, lane = t & 63;
  int r0 = (wave >> 1) * 32, c0 = (wave & 1) * 64;
  int lr = lane & 15;
  int lk = (lane >> 4) * 8;
  int rowreg = (lane >> 4) * 4;

  f32x4 acc[2][4];

  // G1: D1[a][i] = sum_j V[j][a] * B[i][j]
  gemm128(Vb, Ab, r0, c0, lr, lk, acc);
  __syncthreads();
  #pragma unroll
  for (int fr = 0; fr < 2; ++fr)
    #pragma unroll
    for (int fc = 0; fc < 4; ++fc)
      #pragma unroll
      for (int r = 0; r < 4; ++r)
        Ab[r0 + fr * 16 + rowreg + r][c0 + fc * 16 + lr] = f2bf(acc[fr][fc][r]);
  __syncthreads();

  // G2: D2 = D1 * V  (then ./E, E symmetric)
  gemm128(Ab, Vb, r0, c0, lr, lk, acc);
  #pragma unroll
  for (int fr = 0; fr < 2; ++fr)
    #pragma unroll
    for (int fc = 0; fc < 4; ++fc)
      #pragma unroll
      for (int r = 0; r < 4; ++r) {
        int a = r0 + fr * 16 + rowreg + r;
        int bcol = c0 + fc * 16 + lr;
        acc[fr][fc][r] *= rte[(size_t)kk * 16384 + a * 128 + bcol];
      }
  __syncthreads();
  // store transposed; reload Vb = Vh
  #pragma unroll
  for (int fr = 0; fr < 2; ++fr)
    #pragma unroll
    for (int fc = 0; fc < 4; ++fc) {
      int bcol = c0 + fc * 16 + lr;
      int abase = r0 + fr * 16 + rowreg;
      uint32_t lo = (uint32_t)f2bf(acc[fr][fc][0]) | ((uint32_t)f2bf(acc[fr][fc][1]) << 16);
      uint32_t hi = (uint32_t)f2bf(acc[fr][fc][2]) | ((uint32_t)f2bf(acc[fr][fc][3]) << 16);
      *(uint2*)&Ab[bcol][abase] = make_uint2(lo, hi);
    }
  {
    const uint4* Vp = (const uint4*)Vhg;
    #pragma unroll
    for (int e = 0; e < 4; ++e) {
      int idx = e * 512 + t;
      int row = idx >> 4, part = idx & 15;
      *(uint4*)&Vb[row][part * 8] = Vp[idx];
    }
  }
  __syncthreads();

  // G3
  gemm128(Vb, Ab, r0, c0, lr, lk, acc);
  __syncthreads();
  #pragma unroll
  for (int fr = 0; fr < 2; ++fr)
    #pragma unroll
    for (int fc = 0; fc < 4; ++fc)
      #pragma unroll
      for (int r = 0; r < 4; ++r)
        Ab[r0 + fr * 16 + rowreg + r][c0 + fc * 16 + lr] = f2bf(acc[fr][fc][r]);
  __syncthreads();

  // G4
  gemm128(Ab, Vb, r0, c0, lr, lk, acc);
  __syncthreads();
  #pragma unroll
  for (int fr = 0; fr < 2; ++fr)
    #pragma unroll
    for (int fc = 0; fc < 4; ++fc)
      #pragma unroll
      for (int r = 0; r < 4; ++r)
        Ab[r0 + fr * 16 + rowreg + r][c0 + fc * 16 + lr] = f2bf(acc[fr][fc][r]);
  __syncthreads();

  // coalesced bf16 U write
  {
    const size_t ub = (size_t)blk * 16384;
    #pragma unroll
    for (int e = 0; e < 4; ++e) {
      int idx = e * 512 + t;
      int row = idx >> 4, part = idx & 15;
      *(uint4*)(U + ub + row * 128 + part * 8) = *(const uint4*)&Ab[row][part * 8];
    }
  }
}

// ---------------- k5: un-transpose + marker un-rotate ----------------
// block: 32 consecutive ji' (= j*128+i), 16-mm chunk; 256 threads.
__global__ __launch_bounds__(256) void k5_unrot_t(
    const ushort_t* __restrict__ U, const float* __restrict__ VC, float* __restrict__ out) {
  __shared__ ushort_t Us[512 * 40];   // [k*16+mmi][jj], row padded to 80B  40960B
  __shared__ float VCs[1024];         // [c][k]
  int t = threadIdx.x, bid = blockIdx.x;
  int jc = bid >> 2, mt = bid & 3;
  int jip0 = jc * 32, mm0 = mt * 16;

  #pragma unroll
  for (int e = 0; e < 4; ++e) VCs[e * 256 + t] = VC[e * 256 + t];

  #pragma unroll
  for (int e = 0; e < 2; ++e) {
    int row = e * 256 + t;            // k*16 + mmi
    int k = row >> 4, mmi = row & 15;
    const uint4* src = (const uint4*)(U + (size_t)(k * 64 + mm0 + mmi) * 16384 + jip0);
    ushort_t* dst = &Us[row * 40];
    *(uint4*)(dst)      = src[0];
    *(uint4*)(dst + 8)  = src[1];
    *(uint4*)(dst + 16) = src[2];
    *(uint4*)(dst + 24) = src[3];
  }
  __syncthreads();

  int jj = t & 31, cq = t >> 5;
  float acc[4][16];
  #pragma unroll
  for (int e = 0; e < 4; ++e)
    #pragma unroll
    for (int q = 0; q < 16; ++q) acc[e][q] = 0.f;

  for (int k = 0; k < 32; ++k) {
    float y[16];
    #pragma unroll
    for (int q = 0; q < 16; ++q)
      y[q] = bf2f(Us[(k * 16 + q) * 40 + jj]);
    float vc0 = VCs[(cq * 4 + 0) * 32 + k];
    float vc1 = VCs[(cq * 4 + 1) * 32 + k];
    float vc2 = VCs[(cq * 4 + 2) * 32 + k];
    float vc3 = VCs[(cq * 4 + 3) * 32 + k];
    #pragma unroll
    for (int q = 0; q < 16; ++q) {
      acc[0][q] += vc0 * y[q]; acc[1][q] += vc1 * y[q];
      acc[2][q] += vc2 * y[q]; acc[3][q] += vc3 * y[q];
    }
  }

  // ji' = j*128+i  ->  i = (jc&3)*32 + jj, j = jc>>2
  int i = ((jc & 3) << 5) + jj;
  int j = jc >> 2;
  float* ob = out + ((size_t)(i * 128 + j) * 32) * 64 + mm0;
  #pragma unroll
  for (int e = 0; e < 4; ++e) {
    float* oc = ob + (size_t)(cq * 4 + e) * 64;
    *(float4*)(oc)      = make_float4(acc[e][0],  acc[e][1],  acc[e][2],  acc[e][3]);
    *(float4*)(oc + 4)  = make_float4(acc[e][4],  acc[e][5],  acc[e][6],  acc[e][7]);
    *(float4*)(oc + 8)  = make_float4(acc[e][8],  acc[e][9],  acc[e][10], acc[e][11]);
    *(float4*)(oc + 12) = make_float4(acc[e][12], acc[e][13], acc[e][14], acc[e][15]);
  }
}

extern "C" void kernel_launch(void* const* d_in, const int* in_sizes, int n_in,
                              void* d_out, int out_size, void* d_ws, size_t ws_size,
                              hipStream_t stream) {
  (void)in_sizes; (void)n_in; (void)out_size; (void)ws_size;
  const float* v  = (const float*)d_in[0];
  const float* VC = (const float*)d_in[1];
  const float* Vg = (const float*)d_in[2];
  const float* te = (const float*)d_in[3];
  float* out = (float*)d_out;

  char* ws = (char*)d_ws;
  ushort_t* W   = (ushort_t*)(ws);                      // 67,108,864 B
  ushort_t* U   = (ushort_t*)(ws + 67108864);           // 67,108,864 B
  float*    rte = (float*)   (ws + 134217728);          //  2,097,152 B
  ushort_t* Vhg = (ushort_t*)(ws + 136314880);          //     32,768 B
  ushort_t* Vtg = (ushort_t*)(ws + 136347648);          //     32,768 B

  prep_kernel<<<260, 256, 0, stream>>>(te, Vg, rte, Vhg, Vtg);
  k1_rot_t<<<2048, 256, 0, stream>>>(v, VC, W);
  k3_chain<<<2048, 512, 0, stream>>>(W, Vhg, Vtg, rte, U);
  k5_unrot_t<<<2048, 256, 0, stream>>>(U, VC, out);
}